// Round 3
// baseline (741.888 us; speedup 1.0000x reference)
//
#include <hip/hip_runtime.h>

#define DIM    512
#define KCODES 8192
#define NROWS  16384
#define NEG_INF -3.402823466e38f
#define MARGIN 1.0f            // score = dot - e_sq/2 scale; bf16 err std ~0.07
#define CPR 128                // cand slots per row: 32 col-tiles * 2 wm * 2

typedef unsigned short ushort_t;
typedef unsigned int uint_t;
typedef __attribute__((ext_vector_type(8))) short v8s;
typedef __attribute__((ext_vector_type(4))) float v4f;

__device__ inline ushort_t f32_to_bf16_rne(float f) {
    uint_t u = __float_as_uint(f);
    uint_t r = u + 0x7fffu + ((u >> 16) & 1u);
    return (ushort_t)(r >> 16);
}

__device__ inline int4 cvt8hi(float4 a, float4 b) {
    ushort_t h[8] = { f32_to_bf16_rne(a.x), f32_to_bf16_rne(a.y),
                      f32_to_bf16_rne(a.z), f32_to_bf16_rne(a.w),
                      f32_to_bf16_rne(b.x), f32_to_bf16_rne(b.y),
                      f32_to_bf16_rne(b.z), f32_to_bf16_rne(b.w) };
    int4 p;
    p.x = (int)((uint_t)h[0] | ((uint_t)h[1] << 16));
    p.y = (int)((uint_t)h[2] | ((uint_t)h[3] << 16));
    p.z = (int)((uint_t)h[4] | ((uint_t)h[5] << 16));
    p.w = (int)((uint_t)h[6] | ((uint_t)h[7] << 16));
    return p;
}

__device__ inline void dma16(const void* g, void* l) {
    __builtin_amdgcn_global_load_lds(
        (const __attribute__((address_space(1))) unsigned int*)g,
        (__attribute__((address_space(3))) unsigned int*)l, 16, 0, 0);
}

// --------- kernel 0: bf16 convert + norms + k-major TRANSPOSE ---------------
// e_t[sq][8192], x_t[sq][16384] as int4 (8 bf16 per (k-chunk sq, row)).
// LDS transpose, pad 65 + col swizzle (sq + 2r) & 63: both phases
// conflict-free (read-phase lane coefficient 67 ≡ 3 mod 8, odd).
__global__ __launch_bounds__(256) void convert_kernel(
    const float* __restrict__ x, const float* __restrict__ embed,
    int4* __restrict__ e_t, int4* __restrict__ x_t,
    float* __restrict__ e_sq, float* __restrict__ esqh,
    float* __restrict__ f_sq)
{
    __shared__ int4 buf[64][65];   // 66.6 KB

    const int w = threadIdx.x >> 6;
    const int lane = threadIdx.x & 63;
    const bool isE = blockIdx.x < (KCODES / 64);
    const int rows0 = isE ? blockIdx.x * 64 : (blockIdx.x - KCODES / 64) * 64;
    const float* src_base = isE ? embed : x;

    #pragma unroll
    for (int rr = 0; rr < 16; ++rr) {
        int r_local = w * 16 + rr;
        const float* src = src_base + (size_t)(rows0 + r_local) * DIM + lane * 8;
        float4 a = *(const float4*)src;
        float4 b = *(const float4*)(src + 4);
        buf[r_local][(lane + 2 * r_local) & 63] = cvt8hi(a, b);   // sq = lane
        float s = a.x*a.x + a.y*a.y + a.z*a.z + a.w*a.w
                + b.x*b.x + b.y*b.y + b.z*b.z + b.w*b.w;
        #pragma unroll
        for (int off = 32; off >= 1; off >>= 1) s += __shfl_down(s, off, 64);
        if (lane == 0) {
            int r = rows0 + r_local;
            if (isE) { e_sq[r] = s; esqh[r] = -0.5f * s; }
            else     { f_sq[r] = s; }
        }
    }
    __syncthreads();

    #pragma unroll
    for (int i = 0; i < 16; ++i) {
        int sq = w * 16 + i;
        int4 v = buf[lane][(sq + 2 * lane) & 63];
        if (isE) e_t[(size_t)sq * KCODES + rows0 + lane] = v;
        else     x_t[(size_t)sq * NROWS  + rows0 + lane] = v;
    }
}

// --------- kernel 1: bf16 MFMA screen — single-buffer LDS, 2 blocks/CU ------
// Grid: 2048 blocks = 64 row-tiles x 32 code-cols (XCD-swizzled).
// Block tile: 256 codes x 256 rows x K=512; 8 waves, wave tile 128x64
// (acc 8x4x4 = 128 regs). 8 slabs of 64-k, SINGLE-buffered LDS (64 KB) so
// TWO blocks fit per CU (160 KB pool). The DMA drain is exposed per block,
// but the co-resident block's MFMA phase covers it (m114 implicit overlap —
// blocks share no barrier). Compute loop identical to the proven round-0
// form (bit-exact). __launch_bounds__(512,4) caps VGPR at 128 (16 waves/CU).
// setprio(1) around MFMA clusters: independent-block regime (attn-like).
// Waves 0-3 stage EH, waves 4-7 stage XH (8 coalesced 1 KB dma16 each).
__global__ __launch_bounds__(512, 4) void screen_kernel(
    const int4* __restrict__ e_t, const int4* __restrict__ x_t,
    const float* __restrict__ esqh,
    float* __restrict__ cand_s, int* __restrict__ cand_i)
{
    __shared__ __align__(16) short EH[8][256][8];   // 32 KB
    __shared__ __align__(16) short XH[8][256][8];   // 32 KB

    const int t = threadIdx.x;
    const int w = t >> 6;          // 0..7
    const int lane = t & 63;
    const int quad = lane >> 4;
    const int l15 = lane & 15;
    const int wm = w & 1;          // code half (128)
    const int wn = w >> 1;         // row quarter (64)

    const int n = blockIdx.x;
    const int xcd = n & 7;
    const int j = n >> 3;
    const int rt = xcd * 8 + (j & 7);
    const int ct = j >> 3;
    const int row0 = rt * 256;
    const int cbase = ct * 256;

    // DMA bases: waves 0-3 -> E codes w*64, waves 4-7 -> X rows (w-4)*64
    const bool isE = w < 4;
    const int4* gbase = isE ? (e_t + cbase + w * 64 + lane)
                            : (x_t + row0 + (w - 4) * 64 + lane);
    const size_t gstride = isE ? KCODES : NROWS;

    v4f acc[8][4];
    #pragma unroll
    for (int mi = 0; mi < 8; ++mi) {
        float4 sd = *(const float4*)(esqh + cbase + wm * 128 + mi * 16 + quad * 4);
        v4f sv = (v4f){sd.x, sd.y, sd.z, sd.w};
        #pragma unroll
        for (int nj = 0; nj < 4; ++nj) acc[mi][nj] = sv;
    }

    auto issue_dma = [&](int S) {
        short* ldst = isE ? &EH[0][(w & 3) * 64][0] : &XH[0][(w & 3) * 64][0];
        #pragma unroll
        for (int q = 0; q < 8; ++q) {
            int sq = S * 8 + q;
            dma16(gbase + (size_t)sq * gstride, ldst + q * 256 * 8);
        }
    };

    for (int S = 0; S < 8; ++S) {
        __syncthreads();               // all reads of slab S-1 complete
        issue_dma(S);
        __syncthreads();               // per-wave vmcnt(0) drain -> slab S resident

        #pragma unroll
        for (int ks = 0; ks < 2; ++ks) {
            const int q = ks * 4 + quad;
            v8s bh[4];
            #pragma unroll
            for (int nj = 0; nj < 4; ++nj)
                bh[nj] = *(const v8s*)(&XH[q][wn * 64 + nj * 16 + l15][0]);
            __builtin_amdgcn_s_setprio(1);
            #pragma unroll
            for (int mi = 0; mi < 8; ++mi) {
                v8s ah = *(const v8s*)(&EH[q][wm * 128 + mi * 16 + l15][0]);
                #pragma unroll
                for (int nj = 0; nj < 4; ++nj)
                    acc[mi][nj] = __builtin_amdgcn_mfma_f32_16x16x32_bf16(ah, bh[nj], acc[mi][nj], 0, 0, 0);
            }
            __builtin_amdgcn_s_setprio(0);
        }
    }

    // ---- epilogue (once): group-8 max -> top-2 of 4 -> quad merge ----------
    #pragma unroll
    for (int nj = 0; nj < 4; ++nj) {
        float b1 = NEG_INF, b2 = NEG_INF;
        int   i1 = 0, i2 = 0;
        #pragma unroll
        for (int g = 0; g < 4; ++g) {
            v4f s0 = acc[2 * g][nj], s1 = acc[2 * g + 1][nj];
            float m = fmaxf(fmaxf(fmaxf(s0[0], s0[1]), fmaxf(s0[2], s0[3])),
                            fmaxf(fmaxf(s1[0], s1[1]), fmaxf(s1[2], s1[3])));
            int gid = cbase + wm * 128 + g * 32 + quad * 4;  // codes gid+{0..3,16..19}
            if (m > b1)      { b2 = b1; i2 = i1; b1 = m; i1 = gid; }
            else if (m > b2) { b2 = m;  i2 = gid; }
        }
        #pragma unroll
        for (int o = 16; o <= 32; o <<= 1) {   // merge across the 4 quads
            float c1 = __shfl_xor(b1, o, 64);
            int   j1 = __shfl_xor(i1, o, 64);
            float c2 = __shfl_xor(b2, o, 64);
            int   j2 = __shfl_xor(i2, o, 64);
            if (c1 > b1) {
                b2 = fmaxf(b1, c2); i2 = (b1 >= c2) ? i1 : j2;
                b1 = c1; i1 = j1;
            } else {
                i2 = (b2 >= c1) ? i2 : j1;
                b2 = fmaxf(b2, c1);
            }
        }
        if (quad == 0) {
            int row = row0 + wn * 64 + nj * 16 + l15;
            size_t b = (size_t)row * CPR + (ct * 4 + wm * 2);
            cand_s[b]     = b1;  cand_i[b]     = i1;
            cand_s[b + 1] = b2;  cand_i[b + 1] = i2;
        }
    }
}

// --------- kernel 2: exact fp32 rescore of surviving groups + gather --------
__global__ __launch_bounds__(256) void rescore_kernel(
    const float* __restrict__ x, const float* __restrict__ embed,
    const float* __restrict__ e_sq, const float* __restrict__ f_sq,
    const float* __restrict__ cand_s, const int* __restrict__ cand_i,
    float* __restrict__ out)
{
    int row = blockIdx.x * 4 + (threadIdx.x >> 6);
    int lane = threadIdx.x & 63;
    size_t cb = (size_t)row * CPR;

    float cs0 = cand_s[cb + lane];
    float cs1 = cand_s[cb + 64 + lane];
    int   ci0 = cand_i[cb + lane];
    int   ci1 = cand_i[cb + 64 + lane];

    float m = fmaxf(cs0, cs1);
    #pragma unroll
    for (int o = 32; o >= 1; o >>= 1) m = fmaxf(m, __shfl_xor(m, o, 64));

    unsigned long long mask0 = __ballot(cs0 >= m - MARGIN);
    unsigned long long mask1 = __ballot(cs1 >= m - MARGIN);

    const float4* xsrc = (const float4*)(x + (size_t)row * DIM + lane * 8);
    float4 xa = xsrc[0], xb = xsrc[1];
    float fsq = f_sq[row];

    float bd = NEG_INF;
    int   bi = 0x7fffffff;

    #pragma unroll
    for (int s = 0; s < 2; ++s) {
        unsigned long long mask = s ? mask1 : mask0;
        while (mask) {
            int p = __ffsll(mask) - 1;
            mask &= mask - 1;
            int base = __shfl(s ? ci1 : ci0, p);
            #pragma unroll
            for (int e8 = 0; e8 < 8; ++e8) {
                int c = base + ((e8 >> 2) << 4) + (e8 & 3);  // {0..3, 16..19}
                const float4* er = (const float4*)(embed + (size_t)c * DIM + lane * 8);
                float4 ea = er[0], eb = er[1];
                float part = xa.x*ea.x + xa.y*ea.y + xa.z*ea.z + xa.w*ea.w
                           + xb.x*eb.x + xb.y*eb.y + xb.z*eb.z + xb.w*eb.w;
                #pragma unroll
                for (int o = 32; o >= 1; o >>= 1) part += __shfl_xor(part, o, 64);
                float d = -((fsq - 2.0f * part) + e_sq[c]);   // np rounding order
                if (d > bd || (d == bd && c < bi)) { bd = d; bi = c; }
            }
        }
    }

    const float4* er = (const float4*)(embed + (size_t)bi * DIM + lane * 8);
    float4 qa = er[0], qb = er[1];
    float4* dst = (float4*)(out + (size_t)row * DIM + lane * 8);
    dst[0] = qa; dst[1] = qb;
    if (lane == 0) out[(size_t)NROWS * DIM + row] = (float)bi;
}

extern "C" void kernel_launch(void* const* d_in, const int* in_sizes, int n_in,
                              void* d_out, int out_size, void* d_ws, size_t ws_size,
                              hipStream_t stream)
{
    const float* x     = (const float*)d_in[0];   // [16384, 512] fp32
    const float* embed = (const float*)d_in[1];   // [8192, 512] fp32
    float* out = (float*)d_out;

    // ws layout (~25 MB), all 16B-aligned
    float* e_sq   = (float*)d_ws;                               // 8192
    float* esqh   = e_sq + KCODES;                              // 8192 (-e_sq/2)
    float* f_sq   = esqh + KCODES;                              // 16384
    float* cand_s = f_sq + NROWS;                               // 16384*128
    int*   cand_i = (int*)(cand_s + (size_t)NROWS * CPR);       // 16384*128
    int4*  e_t    = (int4*)(cand_i + (size_t)NROWS * CPR);      // [64][8192] int4 = 8 MB

    // x_t lives in d_out scratch (16 MB of 33.6 MB); rescore overwrites later.
    int4* x_t = (int4*)d_out;

    (void)in_sizes; (void)n_in; (void)out_size; (void)ws_size;

    convert_kernel<<<(KCODES + NROWS) / 64, 256, 0, stream>>>(
        x, embed, e_t, x_t, e_sq, esqh, f_sq);
    screen_kernel<<<2048, 512, 0, stream>>>(
        e_t, x_t, esqh, cand_s, cand_i);
    rescore_kernel<<<NROWS / 4, 256, 0, stream>>>(
        x, embed, e_sq, f_sq, cand_s, cand_i, out);
}

// Round 4
// 331.333 us; speedup vs baseline: 2.2391x; 2.2391x over previous
//
#include <hip/hip_runtime.h>

#define DIM    512
#define KCODES 8192
#define NROWS  16384
#define NEG_INF -3.402823466e38f
#define MARGIN 1.0f            // score = dot - e_sq/2 scale; bf16 err std ~0.07
#define CPR 128                // cand slots per row: 32 col-tiles * 2 wm * 2

typedef unsigned short ushort_t;
typedef unsigned int uint_t;
typedef __attribute__((ext_vector_type(8))) short v8s;
typedef __attribute__((ext_vector_type(4))) float v4f;

__device__ inline ushort_t f32_to_bf16_rne(float f) {
    uint_t u = __float_as_uint(f);
    uint_t r = u + 0x7fffu + ((u >> 16) & 1u);
    return (ushort_t)(r >> 16);
}

__device__ inline int4 cvt8hi(float4 a, float4 b) {
    ushort_t h[8] = { f32_to_bf16_rne(a.x), f32_to_bf16_rne(a.y),
                      f32_to_bf16_rne(a.z), f32_to_bf16_rne(a.w),
                      f32_to_bf16_rne(b.x), f32_to_bf16_rne(b.y),
                      f32_to_bf16_rne(b.z), f32_to_bf16_rne(b.w) };
    int4 p;
    p.x = (int)((uint_t)h[0] | ((uint_t)h[1] << 16));
    p.y = (int)((uint_t)h[2] | ((uint_t)h[3] << 16));
    p.z = (int)((uint_t)h[4] | ((uint_t)h[5] << 16));
    p.w = (int)((uint_t)h[6] | ((uint_t)h[7] << 16));
    return p;
}

__device__ inline void dma16(const void* g, void* l) {
    __builtin_amdgcn_global_load_lds(
        (const __attribute__((address_space(1))) unsigned int*)g,
        (__attribute__((address_space(3))) unsigned int*)l, 16, 0, 0);
}

// --------- kernel 0: bf16 convert + norms + k-major TRANSPOSE ---------------
// e_t[sq][8192], x_t[sq][16384] as int4 (8 bf16 per (k-chunk sq, row)).
// LDS transpose, pad 65 + col swizzle (sq + 2r) & 63: both phases
// conflict-free (read-phase lane coefficient 67 ≡ 3 mod 8, odd).
__global__ __launch_bounds__(256) void convert_kernel(
    const float* __restrict__ x, const float* __restrict__ embed,
    int4* __restrict__ e_t, int4* __restrict__ x_t,
    float* __restrict__ e_sq, float* __restrict__ esqh,
    float* __restrict__ f_sq)
{
    __shared__ int4 buf[64][65];   // 66.6 KB

    const int w = threadIdx.x >> 6;
    const int lane = threadIdx.x & 63;
    const bool isE = blockIdx.x < (KCODES / 64);
    const int rows0 = isE ? blockIdx.x * 64 : (blockIdx.x - KCODES / 64) * 64;
    const float* src_base = isE ? embed : x;

    #pragma unroll
    for (int rr = 0; rr < 16; ++rr) {
        int r_local = w * 16 + rr;
        const float* src = src_base + (size_t)(rows0 + r_local) * DIM + lane * 8;
        float4 a = *(const float4*)src;
        float4 b = *(const float4*)(src + 4);
        buf[r_local][(lane + 2 * r_local) & 63] = cvt8hi(a, b);   // sq = lane
        float s = a.x*a.x + a.y*a.y + a.z*a.z + a.w*a.w
                + b.x*b.x + b.y*b.y + b.z*b.z + b.w*b.w;
        #pragma unroll
        for (int off = 32; off >= 1; off >>= 1) s += __shfl_down(s, off, 64);
        if (lane == 0) {
            int r = rows0 + r_local;
            if (isE) { e_sq[r] = s; esqh[r] = -0.5f * s; }
            else     { f_sq[r] = s; }
        }
    }
    __syncthreads();

    #pragma unroll
    for (int i = 0; i < 16; ++i) {
        int sq = w * 16 + i;
        int4 v = buf[lane][(sq + 2 * lane) & 63];
        if (isE) e_t[(size_t)sq * KCODES + rows0 + lane] = v;
        else     x_t[(size_t)sq * NROWS  + rows0 + lane] = v;
    }
}

// --------- kernel 1: bf16 MFMA screen — 64-reg accumulator, reg headroom ----
// Grid: 4096 blocks = 128 row-tiles x 32 code-cols (XCD-swizzled). 1 block/CU.
// Block tile: 256 codes x 128 rows x K=512; 8 waves, wave tile 128x32
// (acc 8x2x4 = 64 AGPR). Total regs ~150/256 -> ~100 spare so the compiler
// can software-pipeline next-ks ds_reads under the MFMA burst (round-0's
// 240/256 budget blocked this -> the 2700cyc/slab stall). Schedule is the
// PROVEN round-0 form: 8 slabs of 64-k, dbuf LDS (96 KB), one barrier per
// slab, DMA(S+1) issued right after it. Accumulation order per acc element
// identical to round-0 => bit-identical scores => rescore unchanged.
// Staging: waves 0-3 -> EH (8 x 1KB dma16), waves 4-7 -> XH (4 x 1KB).
__global__ __launch_bounds__(512, 2) void screen_kernel(
    const int4* __restrict__ e_t, const int4* __restrict__ x_t,
    const float* __restrict__ esqh,
    float* __restrict__ cand_s, int* __restrict__ cand_i)
{
    __shared__ __align__(16) short EH[2][8][256][8];   // 64 KB
    __shared__ __align__(16) short XH[2][8][128][8];   // 32 KB

    const int t = threadIdx.x;
    const int w = t >> 6;          // 0..7
    const int lane = t & 63;
    const int quad = lane >> 4;
    const int l15 = lane & 15;
    const int wm = w & 1;          // code half (128)
    const int wn = w >> 1;         // row quarter (32 rows)

    const int n = blockIdx.x;
    const int xcd = n & 7;
    const int j = n >> 3;
    const int rt = xcd * 16 + (j & 15);
    const int ct = j >> 4;
    const int row0 = rt * 128;
    const int cbase = ct * 256;

    const bool isE = w < 4;
    // E: wave (w&3) stages codes (w&3)*64.. for all 8 q-planes (8 dma16)
    // X: wave v=w-4 stages chunks c=v+4i: q=c>>1, half=c&1 (4 dma16)
    const int4* egbase = e_t + cbase + (w & 3) * 64 + lane;
    const int4* xgbase = x_t + row0 + lane;

    v4f acc[8][2];
    #pragma unroll
    for (int mi = 0; mi < 8; ++mi) {
        float4 sd = *(const float4*)(esqh + cbase + wm * 128 + mi * 16 + quad * 4);
        v4f sv = (v4f){sd.x, sd.y, sd.z, sd.w};
        acc[mi][0] = sv;
        acc[mi][1] = sv;
    }

    auto issue_dma = [&](int S) {
        int buf = S & 1;
        if (isE) {
            #pragma unroll
            for (int q = 0; q < 8; ++q)
                dma16(egbase + (size_t)(S * 8 + q) * KCODES,
                      &EH[buf][q][(w & 3) * 64][0]);
        } else {
            int v = w - 4;
            #pragma unroll
            for (int i = 0; i < 4; ++i) {
                int c = v + 4 * i;
                int q = c >> 1, half = c & 1;
                dma16(xgbase + (size_t)(S * 8 + q) * NROWS + half * 64,
                      &XH[buf][q][half * 64][0]);
            }
        }
    };

    issue_dma(0);

    for (int S = 0; S < 8; ++S) {
        __syncthreads();               // drains DMA(S); DMA(S+1) overlaps compute
        if (S < 7) issue_dma(S + 1);
        const int buf = S & 1;

        #pragma unroll
        for (int ks = 0; ks < 2; ++ks) {
            const int q = ks * 4 + quad;
            v8s bh0 = *(const v8s*)(&XH[buf][q][wn * 32 + l15][0]);
            v8s bh1 = *(const v8s*)(&XH[buf][q][wn * 32 + 16 + l15][0]);
            #pragma unroll
            for (int mi = 0; mi < 8; ++mi) {
                v8s ah = *(const v8s*)(&EH[buf][q][wm * 128 + mi * 16 + l15][0]);
                acc[mi][0] = __builtin_amdgcn_mfma_f32_16x16x32_bf16(ah, bh0, acc[mi][0], 0, 0, 0);
                acc[mi][1] = __builtin_amdgcn_mfma_f32_16x16x32_bf16(ah, bh1, acc[mi][1], 0, 0, 0);
            }
        }
    }

    // ---- epilogue (once): group-8 max -> top-2 of 4 -> quad merge ----------
    #pragma unroll
    for (int nj = 0; nj < 2; ++nj) {
        float b1 = NEG_INF, b2 = NEG_INF;
        int   i1 = 0, i2 = 0;
        #pragma unroll
        for (int g = 0; g < 4; ++g) {
            v4f s0 = acc[2 * g][nj], s1 = acc[2 * g + 1][nj];
            float m = fmaxf(fmaxf(fmaxf(s0[0], s0[1]), fmaxf(s0[2], s0[3])),
                            fmaxf(fmaxf(s1[0], s1[1]), fmaxf(s1[2], s1[3])));
            int gid = cbase + wm * 128 + g * 32 + quad * 4;  // codes gid+{0..3,16..19}
            if (m > b1)      { b2 = b1; i2 = i1; b1 = m; i1 = gid; }
            else if (m > b2) { b2 = m;  i2 = gid; }
        }
        #pragma unroll
        for (int o = 16; o <= 32; o <<= 1) {   // merge across the 4 quads
            float c1 = __shfl_xor(b1, o, 64);
            int   j1 = __shfl_xor(i1, o, 64);
            float c2 = __shfl_xor(b2, o, 64);
            int   j2 = __shfl_xor(i2, o, 64);
            if (c1 > b1) {
                b2 = fmaxf(b1, c2); i2 = (b1 >= c2) ? i1 : j2;
                b1 = c1; i1 = j1;
            } else {
                i2 = (b2 >= c1) ? i2 : j1;
                b2 = fmaxf(b2, c1);
            }
        }
        if (quad == 0) {
            int row = row0 + wn * 32 + nj * 16 + l15;
            size_t b = (size_t)row * CPR + (ct * 4 + wm * 2);
            cand_s[b]     = b1;  cand_i[b]     = i1;
            cand_s[b + 1] = b2;  cand_i[b + 1] = i2;
        }
    }
}

// --------- kernel 2: exact fp32 rescore of surviving groups + gather --------
__global__ __launch_bounds__(256) void rescore_kernel(
    const float* __restrict__ x, const float* __restrict__ embed,
    const float* __restrict__ e_sq, const float* __restrict__ f_sq,
    const float* __restrict__ cand_s, const int* __restrict__ cand_i,
    float* __restrict__ out)
{
    int row = blockIdx.x * 4 + (threadIdx.x >> 6);
    int lane = threadIdx.x & 63;
    size_t cb = (size_t)row * CPR;

    float cs0 = cand_s[cb + lane];
    float cs1 = cand_s[cb + 64 + lane];
    int   ci0 = cand_i[cb + lane];
    int   ci1 = cand_i[cb + 64 + lane];

    float m = fmaxf(cs0, cs1);
    #pragma unroll
    for (int o = 32; o >= 1; o >>= 1) m = fmaxf(m, __shfl_xor(m, o, 64));

    unsigned long long mask0 = __ballot(cs0 >= m - MARGIN);
    unsigned long long mask1 = __ballot(cs1 >= m - MARGIN);

    const float4* xsrc = (const float4*)(x + (size_t)row * DIM + lane * 8);
    float4 xa = xsrc[0], xb = xsrc[1];
    float fsq = f_sq[row];

    float bd = NEG_INF;
    int   bi = 0x7fffffff;

    #pragma unroll
    for (int s = 0; s < 2; ++s) {
        unsigned long long mask = s ? mask1 : mask0;
        while (mask) {
            int p = __ffsll(mask) - 1;
            mask &= mask - 1;
            int base = __shfl(s ? ci1 : ci0, p);
            #pragma unroll
            for (int e8 = 0; e8 < 8; ++e8) {
                int c = base + ((e8 >> 2) << 4) + (e8 & 3);  // {0..3, 16..19}
                const float4* er = (const float4*)(embed + (size_t)c * DIM + lane * 8);
                float4 ea = er[0], eb = er[1];
                float part = xa.x*ea.x + xa.y*ea.y + xa.z*ea.z + xa.w*ea.w
                           + xb.x*eb.x + xb.y*eb.y + xb.z*eb.z + xb.w*eb.w;
                #pragma unroll
                for (int o = 32; o >= 1; o >>= 1) part += __shfl_xor(part, o, 64);
                float d = -((fsq - 2.0f * part) + e_sq[c]);   // np rounding order
                if (d > bd || (d == bd && c < bi)) { bd = d; bi = c; }
            }
        }
    }

    const float4* er = (const float4*)(embed + (size_t)bi * DIM + lane * 8);
    float4 qa = er[0], qb = er[1];
    float4* dst = (float4*)(out + (size_t)row * DIM + lane * 8);
    dst[0] = qa; dst[1] = qb;
    if (lane == 0) out[(size_t)NROWS * DIM + row] = (float)bi;
}

extern "C" void kernel_launch(void* const* d_in, const int* in_sizes, int n_in,
                              void* d_out, int out_size, void* d_ws, size_t ws_size,
                              hipStream_t stream)
{
    const float* x     = (const float*)d_in[0];   // [16384, 512] fp32
    const float* embed = (const float*)d_in[1];   // [8192, 512] fp32
    float* out = (float*)d_out;

    // ws layout (~25 MB), all 16B-aligned
    float* e_sq   = (float*)d_ws;                               // 8192
    float* esqh   = e_sq + KCODES;                              // 8192 (-e_sq/2)
    float* f_sq   = esqh + KCODES;                              // 16384
    float* cand_s = f_sq + NROWS;                               // 16384*128
    int*   cand_i = (int*)(cand_s + (size_t)NROWS * CPR);       // 16384*128
    int4*  e_t    = (int4*)(cand_i + (size_t)NROWS * CPR);      // [64][8192] int4 = 8 MB

    // x_t lives in d_out scratch (16 MB of 33.6 MB); rescore overwrites later.
    int4* x_t = (int4*)d_out;

    (void)in_sizes; (void)n_in; (void)out_size; (void)ws_size;

    convert_kernel<<<(KCODES + NROWS) / 64, 256, 0, stream>>>(
        x, embed, e_t, x_t, e_sq, esqh, f_sq);
    screen_kernel<<<4096, 512, 0, stream>>>(
        e_t, x_t, esqh, cand_s, cand_i);
    rescore_kernel<<<NROWS / 4, 256, 0, stream>>>(
        x, embed, e_sq, f_sq, cand_s, cand_i, out);
}

// Round 5
// 260.753 us; speedup vs baseline: 2.8452x; 1.2707x over previous
//
#include <hip/hip_runtime.h>

#define DIM    512
#define KCODES 8192
#define NROWS  16384
#define NEG_INF -3.402823466e38f
#define MARGIN 1.0f            // score = dot - e_sq/2 scale; bf16 err std ~0.07
#define CPR 128                // cand slots per row: 32 col-tiles * 2 wm * 2

typedef unsigned short ushort_t;
typedef unsigned int uint_t;
typedef __attribute__((ext_vector_type(8))) short v8s;
typedef __attribute__((ext_vector_type(4))) float v4f;

__device__ inline ushort_t f32_to_bf16_rne(float f) {
    uint_t u = __float_as_uint(f);
    uint_t r = u + 0x7fffu + ((u >> 16) & 1u);
    return (ushort_t)(r >> 16);
}

__device__ inline int4 cvt8hi(float4 a, float4 b) {
    ushort_t h[8] = { f32_to_bf16_rne(a.x), f32_to_bf16_rne(a.y),
                      f32_to_bf16_rne(a.z), f32_to_bf16_rne(a.w),
                      f32_to_bf16_rne(b.x), f32_to_bf16_rne(b.y),
                      f32_to_bf16_rne(b.z), f32_to_bf16_rne(b.w) };
    int4 p;
    p.x = (int)((uint_t)h[0] | ((uint_t)h[1] << 16));
    p.y = (int)((uint_t)h[2] | ((uint_t)h[3] << 16));
    p.z = (int)((uint_t)h[4] | ((uint_t)h[5] << 16));
    p.w = (int)((uint_t)h[6] | ((uint_t)h[7] << 16));
    return p;
}

__device__ inline void dma16(const void* g, void* l) {
    __builtin_amdgcn_global_load_lds(
        (const __attribute__((address_space(1))) unsigned int*)g,
        (__attribute__((address_space(3))) unsigned int*)l, 16, 0, 0);
}

// --------- kernel 0: bf16 convert + norms + k-major TRANSPOSE ---------------
// e_t[sq][8192], x_t[sq][16384] as int4 (8 bf16 per (k-chunk sq, row)).
// LDS transpose, pad 65 + col swizzle (sq + 2r) & 63: both phases
// conflict-free (read-phase lane coefficient 67 ≡ 3 mod 8, odd).
// 512 threads (8 waves): halves each thread's serial load->cvt->reduce chain
// vs the 256-thr version and doubles machine-wide waves (latency-bound fix).
// Per-row math order identical => bit-identical outputs.
__global__ __launch_bounds__(512) void convert_kernel(
    const float* __restrict__ x, const float* __restrict__ embed,
    int4* __restrict__ e_t, int4* __restrict__ x_t,
    float* __restrict__ e_sq, float* __restrict__ esqh,
    float* __restrict__ f_sq)
{
    __shared__ int4 buf[64][65];   // 66.6 KB

    const int w = threadIdx.x >> 6;        // 0..7
    const int lane = threadIdx.x & 63;
    const bool isE = blockIdx.x < (KCODES / 64);
    const int rows0 = isE ? blockIdx.x * 64 : (blockIdx.x - KCODES / 64) * 64;
    const float* src_base = isE ? embed : x;

    #pragma unroll
    for (int rr = 0; rr < 8; ++rr) {
        int r_local = w * 8 + rr;
        const float* src = src_base + (size_t)(rows0 + r_local) * DIM + lane * 8;
        float4 a = *(const float4*)src;
        float4 b = *(const float4*)(src + 4);
        buf[r_local][(lane + 2 * r_local) & 63] = cvt8hi(a, b);   // sq = lane
        float s = a.x*a.x + a.y*a.y + a.z*a.z + a.w*a.w
                + b.x*b.x + b.y*b.y + b.z*b.z + b.w*b.w;
        #pragma unroll
        for (int off = 32; off >= 1; off >>= 1) s += __shfl_down(s, off, 64);
        if (lane == 0) {
            int r = rows0 + r_local;
            if (isE) { e_sq[r] = s; esqh[r] = -0.5f * s; }
            else     { f_sq[r] = s; }
        }
    }
    __syncthreads();

    #pragma unroll
    for (int i = 0; i < 8; ++i) {
        int sq = w * 8 + i;
        int4 v = buf[lane][(sq + 2 * lane) & 63];
        if (isE) e_t[(size_t)sq * KCODES + rows0 + lane] = v;
        else     x_t[(size_t)sq * NROWS  + rows0 + lane] = v;
    }
}

// --------- kernel 1: bf16 MFMA screen — 512 thr, 8 waves, 2 waves/SIMD ------
// (PROVEN round-0 form, verbatim: 137.9 us, MfmaUtil 43.5%. Schedule
// experiments r1-r4 all regressed: 8-phase barriers +10us, A-in-reg vmcnt
// aliasing +28us, 128-reg cap spill +460us, half-row tile +62us.)
// Grid: 2048 blocks = 64 row-tiles x 32 code-cols (XCD-swizzled). 1 block/CU.
// Block tile: 256 codes x 256 rows x K=512; wave tile 128x64 (acc 8x4x4 =
// 128 regs — fits 2 waves/SIMD at 256 regs/wave, no spill). 8 slabs of 64-k,
// dbuf LDS (128 KB), one barrier per slab, next-slab DMA right after it.
// Waves 0-3 stage EH, waves 4-7 stage XH (8 coalesced 1 KB dma16 each).
__global__ __launch_bounds__(512, 2) void screen_kernel(
    const int4* __restrict__ e_t, const int4* __restrict__ x_t,
    const float* __restrict__ esqh,
    float* __restrict__ cand_s, int* __restrict__ cand_i)
{
    __shared__ __align__(16) short EH[2][8][256][8];   // 64 KB
    __shared__ __align__(16) short XH[2][8][256][8];   // 64 KB

    const int t = threadIdx.x;
    const int w = t >> 6;          // 0..7
    const int lane = t & 63;
    const int quad = lane >> 4;
    const int l15 = lane & 15;
    const int wm = w & 1;          // code half (128)
    const int wn = w >> 1;         // row quarter (64)

    const int n = blockIdx.x;
    const int xcd = n & 7;
    const int j = n >> 3;
    const int rt = xcd * 8 + (j & 7);
    const int ct = j >> 3;
    const int row0 = rt * 256;
    const int cbase = ct * 256;

    // DMA bases: waves 0-3 -> E codes w*64, waves 4-7 -> X rows (w-4)*64
    const bool isE = w < 4;
    const int4* gbase = isE ? (e_t + cbase + w * 64 + lane)
                            : (x_t + row0 + (w - 4) * 64 + lane);
    const size_t gstride = isE ? KCODES : NROWS;

    v4f acc[8][4];
    #pragma unroll
    for (int mi = 0; mi < 8; ++mi) {
        float4 sd = *(const float4*)(esqh + cbase + wm * 128 + mi * 16 + quad * 4);
        v4f sv = (v4f){sd.x, sd.y, sd.z, sd.w};
        #pragma unroll
        for (int nj = 0; nj < 4; ++nj) acc[mi][nj] = sv;
    }

    auto issue_dma = [&](int S) {
        int buf = S & 1;
        short* ldst = isE ? &EH[buf][0][(w & 3) * 64][0] : &XH[buf][0][(w & 3) * 64][0];
        #pragma unroll
        for (int q = 0; q < 8; ++q) {
            int sq = S * 8 + q;
            dma16(gbase + (size_t)sq * gstride, ldst + q * 256 * 8);
        }
    };

    issue_dma(0);

    for (int S = 0; S < 8; ++S) {
        __syncthreads();               // drains DMA(S); DMA(S+1) overlaps compute
        if (S < 7) issue_dma(S + 1);
        const int buf = S & 1;

        #pragma unroll
        for (int ks = 0; ks < 2; ++ks) {
            const int q = ks * 4 + quad;
            v8s bh[4];
            #pragma unroll
            for (int nj = 0; nj < 4; ++nj)
                bh[nj] = *(const v8s*)(&XH[buf][q][wn * 64 + nj * 16 + l15][0]);
            #pragma unroll
            for (int mi = 0; mi < 8; ++mi) {
                v8s ah = *(const v8s*)(&EH[buf][q][wm * 128 + mi * 16 + l15][0]);
                #pragma unroll
                for (int nj = 0; nj < 4; ++nj)
                    acc[mi][nj] = __builtin_amdgcn_mfma_f32_16x16x32_bf16(ah, bh[nj], acc[mi][nj], 0, 0, 0);
            }
        }
    }

    // ---- epilogue (once): group-8 max -> top-2 of 4 -> quad merge ----------
    #pragma unroll
    for (int nj = 0; nj < 4; ++nj) {
        float b1 = NEG_INF, b2 = NEG_INF;
        int   i1 = 0, i2 = 0;
        #pragma unroll
        for (int g = 0; g < 4; ++g) {
            v4f s0 = acc[2 * g][nj], s1 = acc[2 * g + 1][nj];
            float m = fmaxf(fmaxf(fmaxf(s0[0], s0[1]), fmaxf(s0[2], s0[3])),
                            fmaxf(fmaxf(s1[0], s1[1]), fmaxf(s1[2], s1[3])));
            int gid = cbase + wm * 128 + g * 32 + quad * 4;  // codes gid+{0..3,16..19}
            if (m > b1)      { b2 = b1; i2 = i1; b1 = m; i1 = gid; }
            else if (m > b2) { b2 = m;  i2 = gid; }
        }
        #pragma unroll
        for (int o = 16; o <= 32; o <<= 1) {   // merge across the 4 quads
            float c1 = __shfl_xor(b1, o, 64);
            int   j1 = __shfl_xor(i1, o, 64);
            float c2 = __shfl_xor(b2, o, 64);
            int   j2 = __shfl_xor(i2, o, 64);
            if (c1 > b1) {
                b2 = fmaxf(b1, c2); i2 = (b1 >= c2) ? i1 : j2;
                b1 = c1; i1 = j1;
            } else {
                i2 = (b2 >= c1) ? i2 : j1;
                b2 = fmaxf(b2, c1);
            }
        }
        if (quad == 0) {
            int row = row0 + wn * 64 + nj * 16 + l15;
            size_t b = (size_t)row * CPR + (ct * 4 + wm * 2);
            cand_s[b]     = b1;  cand_i[b]     = i1;
            cand_s[b + 1] = b2;  cand_i[b + 1] = i2;
        }
    }
}

// --------- kernel 2: exact fp32 rescore of surviving groups + gather --------
// Per surviving group: batch-load all 8 embed rows into regs (loads pipeline
// in vmcnt) THEN reduce — breaks the serial load->6-shfl->load chain.
// Iteration order and tie-breaking unchanged => bit-identical selection.
__global__ __launch_bounds__(256) void rescore_kernel(
    const float* __restrict__ x, const float* __restrict__ embed,
    const float* __restrict__ e_sq, const float* __restrict__ f_sq,
    const float* __restrict__ cand_s, const int* __restrict__ cand_i,
    float* __restrict__ out)
{
    int row = blockIdx.x * 4 + (threadIdx.x >> 6);
    int lane = threadIdx.x & 63;
    size_t cb = (size_t)row * CPR;

    float cs0 = cand_s[cb + lane];
    float cs1 = cand_s[cb + 64 + lane];
    int   ci0 = cand_i[cb + lane];
    int   ci1 = cand_i[cb + 64 + lane];

    float m = fmaxf(cs0, cs1);
    #pragma unroll
    for (int o = 32; o >= 1; o >>= 1) m = fmaxf(m, __shfl_xor(m, o, 64));

    unsigned long long mask0 = __ballot(cs0 >= m - MARGIN);
    unsigned long long mask1 = __ballot(cs1 >= m - MARGIN);

    const float4* xsrc = (const float4*)(x + (size_t)row * DIM + lane * 8);
    float4 xa = xsrc[0], xb = xsrc[1];
    float fsq = f_sq[row];

    float bd = NEG_INF;
    int   bi = 0x7fffffff;

    #pragma unroll
    for (int s = 0; s < 2; ++s) {
        unsigned long long mask = s ? mask1 : mask0;
        while (mask) {
            int p = __ffsll(mask) - 1;
            mask &= mask - 1;
            int base = __shfl(s ? ci1 : ci0, p);
            float4 EA[8], EB[8];
            #pragma unroll
            for (int e8 = 0; e8 < 8; ++e8) {
                int c = base + ((e8 >> 2) << 4) + (e8 & 3);  // {0..3, 16..19}
                const float4* er = (const float4*)(embed + (size_t)c * DIM + lane * 8);
                EA[e8] = er[0]; EB[e8] = er[1];
            }
            #pragma unroll
            for (int e8 = 0; e8 < 8; ++e8) {
                int c = base + ((e8 >> 2) << 4) + (e8 & 3);
                float part = xa.x*EA[e8].x + xa.y*EA[e8].y + xa.z*EA[e8].z + xa.w*EA[e8].w
                           + xb.x*EB[e8].x + xb.y*EB[e8].y + xb.z*EB[e8].z + xb.w*EB[e8].w;
                #pragma unroll
                for (int o = 32; o >= 1; o >>= 1) part += __shfl_xor(part, o, 64);
                float d = -((fsq - 2.0f * part) + e_sq[c]);   // np rounding order
                if (d > bd || (d == bd && c < bi)) { bd = d; bi = c; }
            }
        }
    }

    const float4* er = (const float4*)(embed + (size_t)bi * DIM + lane * 8);
    float4 qa = er[0], qb = er[1];
    float4* dst = (float4*)(out + (size_t)row * DIM + lane * 8);
    dst[0] = qa; dst[1] = qb;
    if (lane == 0) out[(size_t)NROWS * DIM + row] = (float)bi;
}

extern "C" void kernel_launch(void* const* d_in, const int* in_sizes, int n_in,
                              void* d_out, int out_size, void* d_ws, size_t ws_size,
                              hipStream_t stream)
{
    const float* x     = (const float*)d_in[0];   // [16384, 512] fp32
    const float* embed = (const float*)d_in[1];   // [8192, 512] fp32
    float* out = (float*)d_out;

    // ws layout (~25 MB), all 16B-aligned
    float* e_sq   = (float*)d_ws;                               // 8192
    float* esqh   = e_sq + KCODES;                              // 8192 (-e_sq/2)
    float* f_sq   = esqh + KCODES;                              // 16384
    float* cand_s = f_sq + NROWS;                               // 16384*128
    int*   cand_i = (int*)(cand_s + (size_t)NROWS * CPR);       // 16384*128
    int4*  e_t    = (int4*)(cand_i + (size_t)NROWS * CPR);      // [64][8192] int4 = 8 MB

    // x_t lives in d_out scratch (16 MB of 33.6 MB); rescore overwrites later.
    int4* x_t = (int4*)d_out;

    (void)in_sizes; (void)n_in; (void)out_size; (void)ws_size;

    convert_kernel<<<(KCODES + NROWS) / 64, 512, 0, stream>>>(
        x, embed, e_t, x_t, e_sq, esqh, f_sq);
    screen_kernel<<<2048, 512, 0, stream>>>(
        e_t, x_t, esqh, cand_s, cand_i);
    rescore_kernel<<<NROWS / 4, 256, 0, stream>>>(
        x, embed, e_sq, f_sq, cand_s, cand_i, out);
}

// Round 6
// 260.268 us; speedup vs baseline: 2.8505x; 1.0019x over previous
//
#include <hip/hip_runtime.h>

#define DIM    512
#define KCODES 8192
#define NROWS  16384
#define NEG_INF -3.402823466e38f
#define MARGIN 4.0f            // i8 screen: pairwise err std ~0.34 -> 12 sigma
#define CPR 128                // cand slots per row: 32 col-tiles * 2 wm * 2

typedef unsigned short ushort_t;
typedef unsigned int uint_t;
typedef __attribute__((ext_vector_type(4))) int   v4i;
typedef __attribute__((ext_vector_type(4))) float v4f;

__device__ inline void dma16(const void* g, void* l) {
    __builtin_amdgcn_global_load_lds(
        (const __attribute__((address_space(1))) unsigned int*)g,
        (__attribute__((address_space(3))) unsigned int*)l, 16, 0, 0);
}

// --------- kernel 0: i8 quantize + norms + scales + k-major TRANSPOSE -------
// e_t8[sq16][8192], x_t8[sq16][16384] as int4 = 16 i8 (k-chunk of 16, row).
// Per-row scale = absmax/127 (exact coverage, no clamp needed).
// Byte LDS transpose buf[64][528]: write int pairs (stride 132 words, lane
// stride 2 words); read int4 at [lane][16*sq] (4-word lane stride — same
// class as screen's measured-0-conflict reads). e_sq/esqh/f_sq fp32 exact,
// same shfl tree as before (lane-0 value bit-identical).
__global__ __launch_bounds__(512) void convert_kernel(
    const float* __restrict__ x, const float* __restrict__ embed,
    int4* __restrict__ e_t8, int4* __restrict__ x_t8,
    float* __restrict__ e_sq, float* __restrict__ esqh,
    float* __restrict__ f_sq,
    float* __restrict__ e_scale, float* __restrict__ f_scale)
{
    __shared__ __align__(16) char buf[64][528];   // 33 KB

    const int w = threadIdx.x >> 6;        // 0..7
    const int lane = threadIdx.x & 63;
    const bool isE = blockIdx.x < (KCODES / 64);
    const int rows0 = isE ? blockIdx.x * 64 : (blockIdx.x - KCODES / 64) * 64;
    const float* src_base = isE ? embed : x;

    #pragma unroll
    for (int rr = 0; rr < 8; ++rr) {
        int r_local = w * 8 + rr;
        const float* src = src_base + (size_t)(rows0 + r_local) * DIM + lane * 8;
        float4 a = *(const float4*)src;
        float4 b = *(const float4*)(src + 4);
        float s = a.x*a.x + a.y*a.y + a.z*a.z + a.w*a.w
                + b.x*b.x + b.y*b.y + b.z*b.z + b.w*b.w;
        float am = fmaxf(fmaxf(fmaxf(fabsf(a.x), fabsf(a.y)), fmaxf(fabsf(a.z), fabsf(a.w))),
                         fmaxf(fmaxf(fabsf(b.x), fabsf(b.y)), fmaxf(fabsf(b.z), fabsf(b.w))));
        #pragma unroll
        for (int off = 32; off >= 1; off >>= 1) {
            s += __shfl_xor(s, off, 64);
            am = fmaxf(am, __shfl_xor(am, off, 64));
        }
        float inv = (am > 0.0f) ? 127.0f / am : 0.0f;

        float vq[8] = {a.x, a.y, a.z, a.w, b.x, b.y, b.z, b.w};
        uint_t lo = 0, hi = 0;
        #pragma unroll
        for (int jj = 0; jj < 4; ++jj) {
            lo |= ((uint_t)((int)rintf(vq[jj]     * inv) & 0xff)) << (8 * jj);
            hi |= ((uint_t)((int)rintf(vq[4 + jj] * inv) & 0xff)) << (8 * jj);
        }
        *(int*)&buf[r_local][8 * lane]     = (int)lo;
        *(int*)&buf[r_local][8 * lane + 4] = (int)hi;

        if (lane == 0) {
            int r = rows0 + r_local;
            float sc = am * (1.0f / 127.0f);
            if (isE) { e_sq[r] = s; esqh[r] = -0.5f * s; e_scale[r] = sc; }
            else     { f_sq[r] = s; f_scale[r] = sc; }
        }
    }
    __syncthreads();

    #pragma unroll
    for (int i = 0; i < 4; ++i) {
        int sq = w * 4 + i;                 // 0..31 k-chunks of 16
        int4 v = *(const int4*)&buf[lane][16 * sq];
        if (isE) e_t8[(size_t)sq * KCODES + rows0 + lane] = v;
        else     x_t8[(size_t)sq * NROWS  + rows0 + lane] = v;
    }
}

// --------- kernel 1: i8 MFMA screen — r0 schedule, half the traffic --------
// Grid: 2048 blocks = 64 row-tiles x 32 code-cols (XCD-swizzled). 1 block/CU.
// Block tile: 256 codes x 256 rows x K=512; wave tile 128x64, acc v4i[8][4]
// = 128 regs (2 waves/SIMD). 4 slabs of K=128 (8 k16-planes each), dbuf LDS
// (128 KB — same as r0), one barrier per slab (half the barriers of r0),
// next-slab DMA right after it. Waves 0-3 stage EH, 4-7 XH (8 x 1KB dma16).
// i8 dot is exact int32; epilogue applies s_f*s_e*idot + (-e_sq/2) in fp32.
// A/B k-chunks both use plane q=ks*4+quad -> permutation-consistent.
__global__ __launch_bounds__(512, 2) void screen_kernel(
    const int4* __restrict__ e_t8, const int4* __restrict__ x_t8,
    const float* __restrict__ esqh,
    const float* __restrict__ e_scale, const float* __restrict__ f_scale,
    float* __restrict__ cand_s, int* __restrict__ cand_i)
{
    __shared__ __align__(16) char EH[2][8][256][16];   // 64 KB
    __shared__ __align__(16) char XH[2][8][256][16];   // 64 KB

    const int t = threadIdx.x;
    const int w = t >> 6;          // 0..7
    const int lane = t & 63;
    const int quad = lane >> 4;
    const int l15 = lane & 15;
    const int wm = w & 1;          // code half (128)
    const int wn = w >> 1;         // row quarter (64)

    const int n = blockIdx.x;
    const int xcd = n & 7;
    const int j = n >> 3;
    const int rt = xcd * 8 + (j & 7);
    const int ct = j >> 3;
    const int row0 = rt * 256;
    const int cbase = ct * 256;

    const bool isE = w < 4;
    const int4* gbase = isE ? (e_t8 + cbase + w * 64 + lane)
                            : (x_t8 + row0 + (w - 4) * 64 + lane);
    const size_t gstride = isE ? KCODES : NROWS;

    v4i acc[8][4];
    #pragma unroll
    for (int mi = 0; mi < 8; ++mi)
        #pragma unroll
        for (int nj = 0; nj < 4; ++nj)
            acc[mi][nj] = (v4i){0, 0, 0, 0};

    auto issue_dma = [&](int S) {
        int buf = S & 1;
        char* ldst = isE ? &EH[buf][0][(w & 3) * 64][0] : &XH[buf][0][(w & 3) * 64][0];
        #pragma unroll
        for (int q = 0; q < 8; ++q) {
            int sq = S * 8 + q;                    // global k16-plane 0..31
            dma16(gbase + (size_t)sq * gstride, ldst + q * 256 * 16);
        }
    };

    issue_dma(0);

    for (int S = 0; S < 4; ++S) {
        __syncthreads();               // drains DMA(S); DMA(S+1) overlaps compute
        if (S < 3) issue_dma(S + 1);
        const int buf = S & 1;

        #pragma unroll
        for (int ks = 0; ks < 2; ++ks) {
            const int q = ks * 4 + quad;
            v4i bh[4];
            #pragma unroll
            for (int nj = 0; nj < 4; ++nj)
                bh[nj] = *(const v4i*)(&XH[buf][q][wn * 64 + nj * 16 + l15][0]);
            #pragma unroll
            for (int mi = 0; mi < 8; ++mi) {
                v4i ah = *(const v4i*)(&EH[buf][q][wm * 128 + mi * 16 + l15][0]);
                #pragma unroll
                for (int nj = 0; nj < 4; ++nj)
                    acc[mi][nj] = __builtin_amdgcn_mfma_i32_16x16x64_i8(ah, bh[nj], acc[mi][nj], 0, 0, 0);
            }
        }
    }

    // ---- epilogue: fp32 scores = sf*se*idot + esqh; top-2 of 4; quad merge --
    v4f se4[8], eq4[8];
    #pragma unroll
    for (int mi = 0; mi < 8; ++mi) {
        se4[mi] = *(const v4f*)(e_scale + cbase + wm * 128 + mi * 16 + quad * 4);
        eq4[mi] = *(const v4f*)(esqh    + cbase + wm * 128 + mi * 16 + quad * 4);
    }

    #pragma unroll
    for (int nj = 0; nj < 4; ++nj) {
        float sfv = f_scale[row0 + wn * 64 + nj * 16 + l15];
        float b1 = NEG_INF, b2 = NEG_INF;
        int   i1 = 0, i2 = 0;
        #pragma unroll
        for (int g = 0; g < 4; ++g) {
            float m = NEG_INF;
            #pragma unroll
            for (int h = 0; h < 2; ++h) {
                int mi = 2 * g + h;
                #pragma unroll
                for (int jj = 0; jj < 4; ++jj) {
                    float sc = fmaf(sfv * se4[mi][jj], (float)acc[mi][nj][jj], eq4[mi][jj]);
                    m = fmaxf(m, sc);
                }
            }
            int gid = cbase + wm * 128 + g * 32 + quad * 4;  // codes gid+{0..3,16..19}
            if (m > b1)      { b2 = b1; i2 = i1; b1 = m; i1 = gid; }
            else if (m > b2) { b2 = m;  i2 = gid; }
        }
        #pragma unroll
        for (int o = 16; o <= 32; o <<= 1) {   // merge across the 4 quads
            float c1 = __shfl_xor(b1, o, 64);
            int   j1 = __shfl_xor(i1, o, 64);
            float c2 = __shfl_xor(b2, o, 64);
            int   j2 = __shfl_xor(i2, o, 64);
            if (c1 > b1) {
                b2 = fmaxf(b1, c2); i2 = (b1 >= c2) ? i1 : j2;
                b1 = c1; i1 = j1;
            } else {
                i2 = (b2 >= c1) ? i2 : j1;
                b2 = fmaxf(b2, c1);
            }
        }
        if (quad == 0) {
            int row = row0 + wn * 64 + nj * 16 + l15;
            size_t b = (size_t)row * CPR + (ct * 4 + wm * 2);
            cand_s[b]     = b1;  cand_i[b]     = i1;
            cand_s[b + 1] = b2;  cand_i[b + 1] = i2;
        }
    }
}

// --------- kernel 2: exact fp32 rescore of surviving groups + gather --------
__global__ __launch_bounds__(256) void rescore_kernel(
    const float* __restrict__ x, const float* __restrict__ embed,
    const float* __restrict__ e_sq, const float* __restrict__ f_sq,
    const float* __restrict__ cand_s, const int* __restrict__ cand_i,
    float* __restrict__ out)
{
    int row = blockIdx.x * 4 + (threadIdx.x >> 6);
    int lane = threadIdx.x & 63;
    size_t cb = (size_t)row * CPR;

    float cs0 = cand_s[cb + lane];
    float cs1 = cand_s[cb + 64 + lane];
    int   ci0 = cand_i[cb + lane];
    int   ci1 = cand_i[cb + 64 + lane];

    float m = fmaxf(cs0, cs1);
    #pragma unroll
    for (int o = 32; o >= 1; o >>= 1) m = fmaxf(m, __shfl_xor(m, o, 64));

    unsigned long long mask0 = __ballot(cs0 >= m - MARGIN);
    unsigned long long mask1 = __ballot(cs1 >= m - MARGIN);

    const float4* xsrc = (const float4*)(x + (size_t)row * DIM + lane * 8);
    float4 xa = xsrc[0], xb = xsrc[1];
    float fsq = f_sq[row];

    float bd = NEG_INF;
    int   bi = 0x7fffffff;

    #pragma unroll
    for (int s = 0; s < 2; ++s) {
        unsigned long long mask = s ? mask1 : mask0;
        while (mask) {
            int p = __ffsll(mask) - 1;
            mask &= mask - 1;
            int base = __shfl(s ? ci1 : ci0, p);
            float4 EA[8], EB[8];
            #pragma unroll
            for (int e8 = 0; e8 < 8; ++e8) {
                int c = base + ((e8 >> 2) << 4) + (e8 & 3);  // {0..3, 16..19}
                const float4* er = (const float4*)(embed + (size_t)c * DIM + lane * 8);
                EA[e8] = er[0]; EB[e8] = er[1];
            }
            #pragma unroll
            for (int e8 = 0; e8 < 8; ++e8) {
                int c = base + ((e8 >> 2) << 4) + (e8 & 3);
                float part = xa.x*EA[e8].x + xa.y*EA[e8].y + xa.z*EA[e8].z + xa.w*EA[e8].w
                           + xb.x*EB[e8].x + xb.y*EB[e8].y + xb.z*EB[e8].z + xb.w*EB[e8].w;
                #pragma unroll
                for (int o = 32; o >= 1; o >>= 1) part += __shfl_xor(part, o, 64);
                float d = -((fsq - 2.0f * part) + e_sq[c]);   // np rounding order
                if (d > bd || (d == bd && c < bi)) { bd = d; bi = c; }
            }
        }
    }

    const float4* er = (const float4*)(embed + (size_t)bi * DIM + lane * 8);
    float4 qa = er[0], qb = er[1];
    float4* dst = (float4*)(out + (size_t)row * DIM + lane * 8);
    dst[0] = qa; dst[1] = qb;
    if (lane == 0) out[(size_t)NROWS * DIM + row] = (float)bi;
}

extern "C" void kernel_launch(void* const* d_in, const int* in_sizes, int n_in,
                              void* d_out, int out_size, void* d_ws, size_t ws_size,
                              hipStream_t stream)
{
    const float* x     = (const float*)d_in[0];   // [16384, 512] fp32
    const float* embed = (const float*)d_in[1];   // [8192, 512] fp32
    float* out = (float*)d_out;

    // ws layout (~21 MB), all 16B-aligned
    float* e_sq    = (float*)d_ws;                              // 8192
    float* esqh    = e_sq + KCODES;                             // 8192 (-e_sq/2)
    float* f_sq    = esqh + KCODES;                             // 16384
    float* e_scale = f_sq + NROWS;                              // 8192
    float* f_scale = e_scale + KCODES;                          // 16384
    float* cand_s  = f_scale + NROWS;                           // 16384*128
    int*   cand_i  = (int*)(cand_s + (size_t)NROWS * CPR);      // 16384*128
    int4*  e_t8    = (int4*)(cand_i + (size_t)NROWS * CPR);     // [32][8192] int4 = 4 MB

    // x_t8 lives in d_out scratch (8 MB of 33.6 MB); rescore overwrites later.
    int4* x_t8 = (int4*)d_out;

    (void)in_sizes; (void)n_in; (void)out_size; (void)ws_size;

    convert_kernel<<<(KCODES + NROWS) / 64, 512, 0, stream>>>(
        x, embed, e_t8, x_t8, e_sq, esqh, f_sq, e_scale, f_scale);
    screen_kernel<<<2048, 512, 0, stream>>>(
        e_t8, x_t8, esqh, e_scale, f_scale, cand_s, cand_i);
    rescore_kernel<<<NROWS / 4, 256, 0, stream>>>(
        x, embed, e_sq, f_sq, cand_s, cand_i, out);
}

// Round 7
// 232.226 us; speedup vs baseline: 3.1947x; 1.1208x over previous
//
#include <hip/hip_runtime.h>

#define DIM    512
#define KCODES 8192
#define NROWS  16384
#define NEG_INF -3.402823466e38f
#define MARGIN 2.0f            // i8 pairwise err std ~0.35 -> 5.7 sigma
#define CPR 128                // cand slots per row: 32 ct * 2 wm * top-2 codes

typedef unsigned short ushort_t;
typedef unsigned int uint_t;
typedef __attribute__((ext_vector_type(4))) int   v4i;
typedef __attribute__((ext_vector_type(4))) float v4f;

__device__ inline void dma16(const void* g, void* l) {
    __builtin_amdgcn_global_load_lds(
        (const __attribute__((address_space(1))) unsigned int*)g,
        (__attribute__((address_space(3))) unsigned int*)l, 16, 0, 0);
}

// --------- kernel 0: i8 quantize + norms + scales + k-major TRANSPOSE -------
// e_t8[sq16][8192], x_t8[sq16][16384] as int4 = 16 i8 (k-chunk of 16, row).
// Per-row scale = absmax/127. Byte LDS transpose buf[64][528]; read phase
// lane word-stride 132 (mod 32 = 4): 8-lane groups tile all 32 banks.
__global__ __launch_bounds__(512) void convert_kernel(
    const float* __restrict__ x, const float* __restrict__ embed,
    int4* __restrict__ e_t8, int4* __restrict__ x_t8,
    float* __restrict__ e_sq, float* __restrict__ esqh,
    float* __restrict__ f_sq,
    float* __restrict__ e_scale, float* __restrict__ f_scale)
{
    __shared__ __align__(16) char buf[64][528];   // 33 KB

    const int w = threadIdx.x >> 6;        // 0..7
    const int lane = threadIdx.x & 63;
    const bool isE = blockIdx.x < (KCODES / 64);
    const int rows0 = isE ? blockIdx.x * 64 : (blockIdx.x - KCODES / 64) * 64;
    const float* src_base = isE ? embed : x;

    #pragma unroll
    for (int rr = 0; rr < 8; ++rr) {
        int r_local = w * 8 + rr;
        const float* src = src_base + (size_t)(rows0 + r_local) * DIM + lane * 8;
        float4 a = *(const float4*)src;
        float4 b = *(const float4*)(src + 4);
        float s = a.x*a.x + a.y*a.y + a.z*a.z + a.w*a.w
                + b.x*b.x + b.y*b.y + b.z*b.z + b.w*b.w;
        float am = fmaxf(fmaxf(fmaxf(fabsf(a.x), fabsf(a.y)), fmaxf(fabsf(a.z), fabsf(a.w))),
                         fmaxf(fmaxf(fabsf(b.x), fabsf(b.y)), fmaxf(fabsf(b.z), fabsf(b.w))));
        #pragma unroll
        for (int off = 32; off >= 1; off >>= 1) {
            s += __shfl_xor(s, off, 64);
            am = fmaxf(am, __shfl_xor(am, off, 64));
        }
        float inv = (am > 0.0f) ? 127.0f / am : 0.0f;

        float vq[8] = {a.x, a.y, a.z, a.w, b.x, b.y, b.z, b.w};
        uint_t lo = 0, hi = 0;
        #pragma unroll
        for (int jj = 0; jj < 4; ++jj) {
            lo |= ((uint_t)((int)rintf(vq[jj]     * inv) & 0xff)) << (8 * jj);
            hi |= ((uint_t)((int)rintf(vq[4 + jj] * inv) & 0xff)) << (8 * jj);
        }
        *(int*)&buf[r_local][8 * lane]     = (int)lo;
        *(int*)&buf[r_local][8 * lane + 4] = (int)hi;

        if (lane == 0) {
            int r = rows0 + r_local;
            float sc = am * (1.0f / 127.0f);
            if (isE) { e_sq[r] = s; esqh[r] = -0.5f * s; e_scale[r] = sc; }
            else     { f_sq[r] = s; f_scale[r] = sc; }
        }
    }
    __syncthreads();

    #pragma unroll
    for (int i = 0; i < 4; ++i) {
        int sq = w * 4 + i;                 // 0..31 k-chunks of 16
        int4 v = *(const int4*)&buf[lane][16 * sq];
        if (isE) e_t8[(size_t)sq * KCODES + rows0 + lane] = v;
        else     x_t8[(size_t)sq * NROWS  + rows0 + lane] = v;
    }
}

// --------- kernel 1: i8 MFMA screen — per-CODE top-2 epilogue ---------------
// Grid: 2048 blocks = 64 row-tiles x 32 code-cols (XCD-swizzled). 1 block/CU.
// Block tile: 256 codes x 256 rows x K=512; wave tile 128x64, acc v4i[8][4]
// = 128 regs (2 waves/SIMD). 4 slabs of K=128 (8 k16-planes each), dbuf LDS
// (128 KB), one barrier per slab, next-slab DMA right after it.
// Epilogue: fp32 score = sf*se*idot + (-e_sq/2) per CODE; top-2 CODES per
// (ct,wm) 128-code window (quads disjoint -> same shfl merge). se/eq loaded
// inside the mi loop (L1) — fixes r6's 53 MB epilogue spill (VGPR budget).
__global__ __launch_bounds__(512, 2) void screen_kernel(
    const int4* __restrict__ e_t8, const int4* __restrict__ x_t8,
    const float* __restrict__ esqh,
    const float* __restrict__ e_scale, const float* __restrict__ f_scale,
    float* __restrict__ cand_s, int* __restrict__ cand_i)
{
    __shared__ __align__(16) char EH[2][8][256][16];   // 64 KB
    __shared__ __align__(16) char XH[2][8][256][16];   // 64 KB

    const int t = threadIdx.x;
    const int w = t >> 6;          // 0..7
    const int lane = t & 63;
    const int quad = lane >> 4;
    const int l15 = lane & 15;
    const int wm = w & 1;          // code half (128)
    const int wn = w >> 1;         // row quarter (64)

    const int n = blockIdx.x;
    const int xcd = n & 7;
    const int j = n >> 3;
    const int rt = xcd * 8 + (j & 7);
    const int ct = j >> 3;
    const int row0 = rt * 256;
    const int cbase = ct * 256;

    const bool isE = w < 4;
    const int4* gbase = isE ? (e_t8 + cbase + w * 64 + lane)
                            : (x_t8 + row0 + (w - 4) * 64 + lane);
    const size_t gstride = isE ? KCODES : NROWS;

    v4i acc[8][4];
    #pragma unroll
    for (int mi = 0; mi < 8; ++mi)
        #pragma unroll
        for (int nj = 0; nj < 4; ++nj)
            acc[mi][nj] = (v4i){0, 0, 0, 0};

    auto issue_dma = [&](int S) {
        int buf = S & 1;
        char* ldst = isE ? &EH[buf][0][(w & 3) * 64][0] : &XH[buf][0][(w & 3) * 64][0];
        #pragma unroll
        for (int q = 0; q < 8; ++q) {
            int sq = S * 8 + q;                    // global k16-plane 0..31
            dma16(gbase + (size_t)sq * gstride, ldst + q * 256 * 16);
        }
    };

    issue_dma(0);

    for (int S = 0; S < 4; ++S) {
        __syncthreads();               // drains DMA(S); DMA(S+1) overlaps compute
        if (S < 3) issue_dma(S + 1);
        const int buf = S & 1;

        #pragma unroll
        for (int ks = 0; ks < 2; ++ks) {
            const int q = ks * 4 + quad;
            v4i bh[4];
            #pragma unroll
            for (int nj = 0; nj < 4; ++nj)
                bh[nj] = *(const v4i*)(&XH[buf][q][wn * 64 + nj * 16 + l15][0]);
            #pragma unroll
            for (int mi = 0; mi < 8; ++mi) {
                v4i ah = *(const v4i*)(&EH[buf][q][wm * 128 + mi * 16 + l15][0]);
                #pragma unroll
                for (int nj = 0; nj < 4; ++nj)
                    acc[mi][nj] = __builtin_amdgcn_mfma_i32_16x16x64_i8(ah, bh[nj], acc[mi][nj], 0, 0, 0);
            }
        }
    }

    // ---- epilogue: per-code fp32 scores -> top-2 codes per window ----------
    #pragma unroll
    for (int nj = 0; nj < 4; ++nj) {
        float sfv = f_scale[row0 + wn * 64 + nj * 16 + l15];
        float b1 = NEG_INF, b2 = NEG_INF;
        int   i1 = 0x7fffffff, i2 = 0x7fffffff;
        #pragma unroll
        for (int mi = 0; mi < 8; ++mi) {
            v4f se4 = *(const v4f*)(e_scale + cbase + wm * 128 + mi * 16 + quad * 4);
            v4f eq4 = *(const v4f*)(esqh    + cbase + wm * 128 + mi * 16 + quad * 4);
            int cid0 = cbase + wm * 128 + mi * 16 + quad * 4;
            #pragma unroll
            for (int jj = 0; jj < 4; ++jj) {
                float sc = fmaf(sfv * se4[jj], (float)acc[mi][nj][jj], eq4[jj]);
                int cc = cid0 + jj;
                if (sc > b1)      { b2 = b1; i2 = i1; b1 = sc; i1 = cc; }
                else if (sc > b2) { b2 = sc; i2 = cc; }
            }
        }
        #pragma unroll
        for (int o = 16; o <= 32; o <<= 1) {   // merge across the 4 quads
            float c1 = __shfl_xor(b1, o, 64);
            int   j1 = __shfl_xor(i1, o, 64);
            float c2 = __shfl_xor(b2, o, 64);
            int   j2 = __shfl_xor(i2, o, 64);
            if (c1 > b1) {
                b2 = fmaxf(b1, c2); i2 = (b1 >= c2) ? i1 : j2;
                b1 = c1; i1 = j1;
            } else {
                i2 = (b2 >= c1) ? i2 : j1;
                b2 = fmaxf(b2, c1);
            }
        }
        if (quad == 0) {
            int row = row0 + wn * 64 + nj * 16 + l15;
            size_t b = (size_t)row * CPR + (ct * 4 + wm * 2);
            cand_s[b]     = b1;  cand_i[b]     = i1;
            cand_s[b + 1] = b2;  cand_i[b + 1] = i2;
        }
    }
}

// --------- kernel 2: exact fp32 rescore of surviving CODES + gather ---------
// One exact 512-dot per surviving code (typically 1-3 per row).
__global__ __launch_bounds__(256) void rescore_kernel(
    const float* __restrict__ x, const float* __restrict__ embed,
    const float* __restrict__ e_sq, const float* __restrict__ f_sq,
    const float* __restrict__ cand_s, const int* __restrict__ cand_i,
    float* __restrict__ out)
{
    int row = blockIdx.x * 4 + (threadIdx.x >> 6);
    int lane = threadIdx.x & 63;
    size_t cb = (size_t)row * CPR;

    float cs0 = cand_s[cb + lane];
    float cs1 = cand_s[cb + 64 + lane];
    int   ci0 = cand_i[cb + lane];
    int   ci1 = cand_i[cb + 64 + lane];

    float m = fmaxf(cs0, cs1);
    #pragma unroll
    for (int o = 32; o >= 1; o >>= 1) m = fmaxf(m, __shfl_xor(m, o, 64));

    unsigned long long mask0 = __ballot(cs0 >= m - MARGIN);
    unsigned long long mask1 = __ballot(cs1 >= m - MARGIN);

    const float4* xsrc = (const float4*)(x + (size_t)row * DIM + lane * 8);
    float4 xa = xsrc[0], xb = xsrc[1];
    float fsq = f_sq[row];

    float bd = NEG_INF;
    int   bi = 0x7fffffff;

    #pragma unroll
    for (int s = 0; s < 2; ++s) {
        unsigned long long mask = s ? mask1 : mask0;
        while (mask) {
            int p = __ffsll(mask) - 1;
            mask &= mask - 1;
            int c = __shfl(s ? ci1 : ci0, p);
            const float4* er = (const float4*)(embed + (size_t)c * DIM + lane * 8);
            float4 ea = er[0], eb = er[1];
            float part = xa.x*ea.x + xa.y*ea.y + xa.z*ea.z + xa.w*ea.w
                       + xb.x*eb.x + xb.y*eb.y + xb.z*eb.z + xb.w*eb.w;
            #pragma unroll
            for (int o = 32; o >= 1; o >>= 1) part += __shfl_xor(part, o, 64);
            float d = -((fsq - 2.0f * part) + e_sq[c]);   // np rounding order
            if (d > bd || (d == bd && c < bi)) { bd = d; bi = c; }
        }
    }

    const float4* er = (const float4*)(embed + (size_t)bi * DIM + lane * 8);
    float4 qa = er[0], qb = er[1];
    float4* dst = (float4*)(out + (size_t)row * DIM + lane * 8);
    dst[0] = qa; dst[1] = qb;
    if (lane == 0) out[(size_t)NROWS * DIM + row] = (float)bi;
}

extern "C" void kernel_launch(void* const* d_in, const int* in_sizes, int n_in,
                              void* d_out, int out_size, void* d_ws, size_t ws_size,
                              hipStream_t stream)
{
    const float* x     = (const float*)d_in[0];   // [16384, 512] fp32
    const float* embed = (const float*)d_in[1];   // [8192, 512] fp32
    float* out = (float*)d_out;

    // ws layout (~21 MB), all 16B-aligned
    float* e_sq    = (float*)d_ws;                              // 8192
    float* esqh    = e_sq + KCODES;                             // 8192 (-e_sq/2)
    float* f_sq    = esqh + KCODES;                             // 16384
    float* e_scale = f_sq + NROWS;                              // 8192
    float* f_scale = e_scale + KCODES;                          // 16384
    float* cand_s  = f_scale + NROWS;                           // 16384*128
    int*   cand_i  = (int*)(cand_s + (size_t)NROWS * CPR);      // 16384*128
    int4*  e_t8    = (int4*)(cand_i + (size_t)NROWS * CPR);     // [32][8192] int4 = 4 MB

    // x_t8 lives in d_out scratch (8 MB of 33.6 MB); rescore overwrites later.
    int4* x_t8 = (int4*)d_out;

    (void)in_sizes; (void)n_in; (void)out_size; (void)ws_size;

    convert_kernel<<<(KCODES + NROWS) / 64, 512, 0, stream>>>(
        x, embed, e_t8, x_t8, e_sq, esqh, f_sq, e_scale, f_scale);
    screen_kernel<<<2048, 512, 0, stream>>>(
        e_t8, x_t8, esqh, e_scale, f_scale, cand_s, cand_i);
    rescore_kernel<<<NROWS / 4, 256, 0, stream>>>(
        x, embed, e_sq, f_sq, cand_s, cand_i, out);
}